// Round 9
// baseline (65.107 us; speedup 1.0000x reference)
//
#include <hip/hip_runtime.h>

#define B_   8192
#define DIN  512
#define DOUT 512
#define NC   8
#define NCD  (NC * DIN)
#define KSPL 4

typedef float  f32x4 __attribute__((ext_vector_type(4)));
typedef short  s16x8 __attribute__((ext_vector_type(8)));
typedef unsigned short u16x4 __attribute__((ext_vector_type(4)));
typedef unsigned int   u32x4 __attribute__((ext_vector_type(4)));

__device__ __forceinline__ unsigned short f2bf(float f) {
  unsigned u = __builtin_bit_cast(unsigned, f);
  u += 0x7fffu + ((u >> 16) & 1u);          // RTNE
  return (unsigned short)(u >> 16);
}
__device__ __forceinline__ float bf2f(unsigned short h) {
  unsigned u = ((unsigned)h) << 16;
  return __builtin_bit_cast(float, u);
}
__device__ __forceinline__ unsigned cvtpk(float lo, float hi) {
  unsigned r;
  asm("v_cvt_pk_bf16_f32 %0, %1, %2" : "=v"(r) : "v"(lo), "v"(hi));
  return r;
}
__device__ __forceinline__ void gl2lds16(const void* g, void* l) {
  __builtin_amdgcn_global_load_lds(
      (const __attribute__((address_space(1))) void*)g,
      (__attribute__((address_space(3))) void*)l, 16, 0, 0);
}

// ---------- fused pack: x (f32->bf16) and w (f32 transpose->bf16) ----------
__global__ void pack_xw_k(const f32x4* __restrict__ x, u16x4* __restrict__ xb,
                          const float* __restrict__ w, unsigned short* __restrict__ Wt) {
  __shared__ float tile[64][65];
  const int tid = threadIdx.x;
  if (blockIdx.x < 4096) {                      // pack x: 4096 blocks
    int gid = blockIdx.x * 256 + tid;
    f32x4 v = x[gid];
    u16x4 o;
    o[0] = f2bf(v[0]); o[1] = f2bf(v[1]); o[2] = f2bf(v[2]); o[3] = f2bf(v[3]);
    xb[gid] = o;
    return;
  }
  const int idx = blockIdx.x - 4096;            // pack w: 512 blocks
  const int kt = idx & 63, nt = idx >> 6;
#pragma unroll
  for (int it = 0; it < 16; ++it) {
    int u = it * 256 + tid;
    int r = u >> 6, cc = u & 63;
    tile[r][cc] = w[(size_t)(kt * 64 + r) * DOUT + nt * 64 + cc];
  }
  __syncthreads();
#pragma unroll
  for (int it = 0; it < 16; ++it) {
    int u = it * 256 + tid;
    int rn = u >> 6, ck = u & 63;
    Wt[(size_t)(nt * 64 + rn) * NCD + kt * 64 + ck] = f2bf(tile[ck][rn]);
  }
}

// ---- fused GEMM: part_s = (wt .* x) @ W', 256x256 tile, K=1024 (split-K 4) ----
// r9: BK=32 half-tile pipeline (m201 granularity). 32 halves; per half:
//   {issue 1 B-half (2 gl2lds) -> counted vmcnt -> BAR -> 12 ds_read_b128 ->
//    [h1: vmcnt(4); SCALE A(t+1); AREGS(t+2)] -> lgkm(0) -> 32 MFMA (setprio)}
// LDS: A = 2 tile-slots x [kk][256 rows][32k] (2x32KB); B = 4 half-slots x
// [256][32k] (4x16KB). Swizzle: phys 16B-chunk = logical ^ (row&3); frag reads
// and scale-writes both 2 lanes/bank (free, m136); gl2lds dest linear with
// source-side swizzle.  vmcnt FIFO audit (steady): issue order
// ...B(2t+1),A(t+1) | B(2t+2) | B(2t+3),A(t+2)...; h0 vmcnt(8) gates B(2t);
// h1 vmcnt(8) gates B(2t+1); h1-mid vmcnt(4) gates A(t+1); tails 2/0.
// Slot reuse: staged slot last read 2 halves (>=1 barrier) earlier; A-writes
// drained by writer's lgkm(0) before it reaches the next BAR.
__global__ __launch_bounds__(512, 2) void gemm_k(
    const unsigned short* __restrict__ xb,   // [B_][DIN] bf16
    const unsigned short* __restrict__ Wt,   // [DOUT][NCD] bf16
    const float* __restrict__ wt,            // [B_][NC] f32
    unsigned short* __restrict__ part) {     // [KSPL][B_][DOUT] bf16
  extern __shared__ char smem[];
  const int tid  = threadIdx.x;
  const int lane = tid & 63, wid = tid >> 6;
  const int wm = wid >> 2, wn = wid & 3;       // 2 x 4 wave grid
  const int l15 = lane & 15, lhi = lane >> 4;

  const int n0   = blockIdx.x;                 // 256 blocks
  const int by   = n0 >> 3;                    // 0..31
  const int bx   = (n0 >> 2) & 1;              // 0..1
  const int ks   = n0 & 3;                     // K-chunk: experts 2ks, 2ks+1
  const int brow = by * 256, bcol = bx * 256;

  // ---- A staging (reg->scale->swizzled ds_write), rows tid>>3 (+64P) ----
  const int srow = tid >> 3, schunk = tid & 7;
  const unsigned short* gA = xb + (size_t)(brow + srow) * DIN + schunk * 8;
  const int adst_off = (schunk >> 2) * 16384 + srow * 64
                     + (((schunk & 3) ^ (srow & 3)) << 4);

  // ---- B staging (gl2lds, linear dest, pre-swizzled source), rows tid>>2 ----
  const int br = tid >> 2, bc = tid & 3;
  const unsigned short* gB0 = Wt + (size_t)(bcol + br) * NCD + ks * 1024
                                 + ((bc ^ (br & 3)) * 8);

  // routing weights for this block's rows x 2 experts (held in VGPRs)
  const float* wtp = wt + (size_t)(brow + srow) * NC + ks * 2;
  const float wtv0_0 = wtp[0],            wtv1_0 = wtp[1];
  const float wtv0_1 = wtp[64 * NC],      wtv1_1 = wtp[64 * NC + 1];
  const float wtv0_2 = wtp[128 * NC],     wtv1_2 = wtp[128 * NC + 1];
  const float wtv0_3 = wtp[192 * NC],     wtv1_3 = wtp[192 * NC + 1];

  f32x4 acc[8][4] = {};
  s16x8 areg0, areg1, areg2, areg3;
  s16x8 a[8], b[4];
  const int key    = (lhi ^ (l15 & 3)) << 4;           // read-side swizzle
  const int abase2 = (wm * 128 + l15) * 64 + key;      // + kk*16384 + m*1024
  const int bbase2 = (wn * 64  + l15) * 64 + key;      // + n*1024

#define STAGE_BH(H) {                                                        \
    const unsigned short* s_ = gB0 + ((H) >> 1) * 64 + ((H) & 1) * 32;       \
    char* l_ = smem + 65536 + ((H) & 3) * 16384 + tid * 16;                  \
    gl2lds16(s_, l_);                                                        \
    gl2lds16(s_ + (size_t)128 * NCD, l_ + 8192); }
#define LOAD_AREGS(kt) {                                                     \
    const unsigned short* s_ = gA + ((kt) & 7) * 64;                         \
    areg0 = *(const s16x8*)(s_);                                             \
    areg1 = *(const s16x8*)(s_ + (size_t) 64 * DIN);                         \
    areg2 = *(const s16x8*)(s_ + (size_t)128 * DIN);                         \
    areg3 = *(const s16x8*)(s_ + (size_t)192 * DIN); }
#define SCALE_STORE(AR, S, P, slotb) {                                       \
    u32x4 v_;                                                                \
    v_[0] = cvtpk(bf2f((unsigned short)AR[0]) * (S),                         \
                  bf2f((unsigned short)AR[1]) * (S));                        \
    v_[1] = cvtpk(bf2f((unsigned short)AR[2]) * (S),                         \
                  bf2f((unsigned short)AR[3]) * (S));                        \
    v_[2] = cvtpk(bf2f((unsigned short)AR[4]) * (S),                         \
                  bf2f((unsigned short)AR[5]) * (S));                        \
    v_[3] = cvtpk(bf2f((unsigned short)AR[6]) * (S),                         \
                  bf2f((unsigned short)AR[7]) * (S));                        \
    *(u32x4*)(smem + (slotb) + adst_off + (P) * 4096) = v_; }
#define SCALE_WRITE_ALL(e_, slotb) {                                         \
    SCALE_STORE(areg0, (e_) ? wtv1_0 : wtv0_0, 0, slotb);                    \
    SCALE_STORE(areg1, (e_) ? wtv1_1 : wtv0_1, 1, slotb);                    \
    SCALE_STORE(areg2, (e_) ? wtv1_2 : wtv0_2, 2, slotb);                    \
    SCALE_STORE(areg3, (e_) ? wtv1_3 : wtv0_3, 3, slotb); }
#define RD_HALF(aslotb, kk, bslot) {                                         \
    const char* pa_ = smem + (aslotb) + (kk) * 16384 + abase2;               \
    const char* pb_ = smem + 65536 + (bslot) * 16384 + bbase2;               \
    _Pragma("unroll") for (int m = 0; m < 8; ++m)                            \
      a[m] = *(const s16x8*)(pa_ + m * 1024);                                \
    _Pragma("unroll") for (int n = 0; n < 4; ++n)                            \
      b[n] = *(const s16x8*)(pb_ + n * 1024); }
#define MFMA_HALF()                                                          \
    _Pragma("unroll") for (int m = 0; m < 8; ++m)                            \
      _Pragma("unroll") for (int n = 0; n < 4; ++n)                          \
        acc[m][n] = __builtin_amdgcn_mfma_f32_16x16x32_bf16(                 \
            a[m], b[n], acc[m][n], 0, 0, 0);
#define BAR()   __builtin_amdgcn_s_barrier()
#define PRIO1() __builtin_amdgcn_s_setprio(1)
#define PRIO0() __builtin_amdgcn_s_setprio(0)
#define PIN()   asm volatile("" ::: "memory")
#define WAITV(N) asm volatile("s_waitcnt vmcnt(" #N ")" ::: "memory")
#define WAITL()  asm volatile("s_waitcnt lgkmcnt(0)" ::: "memory")

  // ---- prologue ----
  PIN();                          // wt loads pinned oldest in vmcnt FIFO
  LOAD_AREGS(0);                  // A(0): 4 loads
  PIN();
  STAGE_BH(0); STAGE_BH(1);       // B halves 0,1: 2+2
  WAITV(4);                       // retires wt + A(0); B(0),B(1) flying
  SCALE_WRITE_ALL(0, 0);          // A(0) -> slot 0
  LOAD_AREGS(1);                  // A(1): 4 loads in flight
  WAITL();                        // scale writes drained before first BAR

  for (int t = 0; t < 16; ++t) {
    const int aslot = (t & 1) * 32768, oslot = 32768 - aslot;
    // ================ half h0 (kk = 0) ================
    if (t < 15) { STAGE_BH(2 * t + 2); WAITV(8); }
    else        { WAITV(2); }
    BAR(); PIN();
    RD_HALF(aslot, 0, (2 * t) & 3);
    WAITL();
    __builtin_amdgcn_sched_barrier(0);
    PRIO1(); MFMA_HALF(); PRIO0();
    // ================ half h1 (kk = 1) ================
    if (t < 15) { STAGE_BH(2 * t + 3); WAITV(8); }
    else        { WAITV(0); }
    BAR(); PIN();
    RD_HALF(aslot, 1, (2 * t + 1) & 3);
    if (t < 15) {
      WAITV(4);                                   // A(t+1) landed
      const int e = (t + 1) >> 3;
      SCALE_WRITE_ALL(e, oslot);
      if (t < 14) LOAD_AREGS(t + 2);
    }
    WAITL();
    __builtin_amdgcn_sched_barrier(0);
    PRIO1(); MFMA_HALF(); PRIO0();
  }

  // ---- epilogue: repack via LDS, then full-line dwordx4 stores ----
  __syncthreads();
  unsigned short* Cs = (unsigned short*)smem;   // [256][264] bf16
#pragma unroll
  for (int m = 0; m < 8; ++m)
#pragma unroll
    for (int n = 0; n < 4; ++n) {
      const int row = wm * 128 + m * 16 + (lane >> 4) * 4;
      const int col = wn * 64 + n * 16 + l15;
      f32x4 v = acc[m][n];
#pragma unroll
      for (int j = 0; j < 4; ++j)
        Cs[(row + j) * 264 + col] = f2bf(v[j]);
    }
  __syncthreads();
  unsigned short* pc = part + (size_t)ks * (B_ * DOUT) + (size_t)brow * DOUT + bcol;
#pragma unroll
  for (int it = 0; it < 16; ++it) {
    const int u = it * 512 + tid;
    const int row = u >> 5, cu = (u & 31) * 8;
    f32x4 v = *(const f32x4*)(Cs + row * 264 + cu);
    *(f32x4*)(pc + (size_t)row * DOUT + cu) = v;
  }
#undef STAGE_BH
#undef LOAD_AREGS
#undef SCALE_STORE
#undef SCALE_WRITE_ALL
#undef RD_HALF
#undef MFMA_HALF
#undef BAR
#undef PRIO1
#undef PRIO0
#undef PIN
#undef WAITV
#undef WAITL
}

// -------- reduce: out = sum_s part_s + sum_c wt[b][c]*bias[c] --------
__global__ void reduce_k(const unsigned short* __restrict__ part,
                         const float* __restrict__ wt,
                         const float* __restrict__ bias,
                         float* __restrict__ out) {
  int gid = blockIdx.x * 256 + threadIdx.x;
  int b = gid >> 7;
  int o4 = (gid & 127) << 2;
  float w8[8];
  *(f32x4*)w8       = *(const f32x4*)(wt + (size_t)b * NC);
  *(f32x4*)(w8 + 4) = *(const f32x4*)(wt + (size_t)b * NC + 4);
  f32x4 acc = {0.f, 0.f, 0.f, 0.f};
  const size_t off = (size_t)b * DOUT + o4;
#pragma unroll
  for (int s = 0; s < KSPL; ++s) {
    u16x4 p = *(const u16x4*)(part + (size_t)s * (B_ * DOUT) + off);
#pragma unroll
    for (int i = 0; i < 4; ++i) acc[i] += bf2f(p[i]);
  }
#pragma unroll
  for (int cc = 0; cc < NC; ++cc) {
    f32x4 bi = *(const f32x4*)(bias + cc * DOUT + o4);
#pragma unroll
    for (int i = 0; i < 4; ++i) acc[i] += w8[cc] * bi[i];
  }
  *(f32x4*)(out + off) = acc;
}

// ---------------- fallback if ws too small ----------------
__global__ void bias_only_k(const float* __restrict__ wt,
                            const float* __restrict__ bias,
                            float* __restrict__ out) {
  int gid = blockIdx.x * 256 + threadIdx.x;
  int b = gid >> 7;
  int o4 = (gid & 127) << 2;
  float w8[8];
  *(f32x4*)w8       = *(const f32x4*)(wt + (size_t)b * NC);
  *(f32x4*)(w8 + 4) = *(const f32x4*)(wt + (size_t)b * NC + 4);
  f32x4 acc = {0.f, 0.f, 0.f, 0.f};
#pragma unroll
  for (int cc = 0; cc < NC; ++cc) {
    f32x4 bi = *(const f32x4*)(bias + cc * DOUT + o4);
#pragma unroll
    for (int i = 0; i < 4; ++i) acc[i] += w8[cc] * bi[i];
  }
  *(f32x4*)(out + (size_t)b * DOUT + o4) = acc;
}

extern "C" void kernel_launch(void* const* d_in, const int* in_sizes, int n_in,
                              void* d_out, int out_size, void* d_ws, size_t ws_size,
                              hipStream_t stream) {
  const float *x = nullptr, *wtc = nullptr, *w = nullptr, *bias = nullptr;
  for (int i = 0; i < n_in; ++i) {
    switch (in_sizes[i]) {
      case B_ * DIN:        x    = (const float*)d_in[i]; break;
      case B_ * NC:         wtc  = (const float*)d_in[i]; break;
      case NC * DIN * DOUT: w    = (const float*)d_in[i]; break;
      case NC * DOUT:       bias = (const float*)d_in[i]; break;
    }
  }
  float* out = (float*)d_out;

  const size_t XB_ELEMS   = (size_t)B_ * DIN;
  const size_t WT_ELEMS   = (size_t)DOUT * NCD;
  const size_t PART_ELEMS = (size_t)KSPL * B_ * DOUT;
  const size_t need = (XB_ELEMS + WT_ELEMS + PART_ELEMS) * sizeof(unsigned short);

  if (ws_size < need) {
    bias_only_k<<<(B_ * DOUT / 4) / 256, 256, 0, stream>>>(wtc, bias, out);
    return;
  }

  unsigned short* xb   = (unsigned short*)d_ws;
  unsigned short* Wt   = xb + XB_ELEMS;
  unsigned short* part = Wt + WT_ELEMS;

  const int GEMM_LDS = 256 * 264 * 2;   // 135168 B (staging uses first 131072)
  (void)hipFuncSetAttribute((const void*)gemm_k,
                            hipFuncAttributeMaxDynamicSharedMemorySize, GEMM_LDS);

  pack_xw_k<<<4096 + 512, 256, 0, stream>>>((const f32x4*)x, (u16x4*)xb, w, Wt);
  gemm_k<<<256, 512, GEMM_LDS, stream>>>(xb, Wt, wtc, part);
  reduce_k<<<(B_ * DOUT / 4) / 256, 256, 0, stream>>>(part, wtc, bias, out);
}

// Round 10
// 62.459 us; speedup vs baseline: 1.0424x; 1.0424x over previous
//
#include <hip/hip_runtime.h>

#define B_   8192
#define DIN  512
#define DOUT 512
#define NC   8
#define NCD  (NC * DIN)
#define KSPL 4

typedef float  f32x4 __attribute__((ext_vector_type(4)));
typedef short  s16x8 __attribute__((ext_vector_type(8)));
typedef unsigned short u16x4 __attribute__((ext_vector_type(4)));
typedef unsigned int   u32x4 __attribute__((ext_vector_type(4)));

__device__ __forceinline__ unsigned short f2bf(float f) {
  unsigned u = __builtin_bit_cast(unsigned, f);
  u += 0x7fffu + ((u >> 16) & 1u);          // RTNE
  return (unsigned short)(u >> 16);
}
__device__ __forceinline__ float bf2f(unsigned short h) {
  unsigned u = ((unsigned)h) << 16;
  return __builtin_bit_cast(float, u);
}
__device__ __forceinline__ unsigned cvtpk(float lo, float hi) {
  unsigned r;
  asm("v_cvt_pk_bf16_f32 %0, %1, %2" : "=v"(r) : "v"(lo), "v"(hi));
  return r;
}

// ---------- fused pack: x (f32->bf16) and w (f32 -> MFMA-frag-order bf16) ----
// WtF element (expert e, col, k) with n16=col>>4, l15=col&15, ktl=(k>>6)&7,
// kk=(k>>5)&1, lhi=(k>>3)&3, j=k&7, lane=lhi*16+l15:
//   WtF[ ((((e*32+n16)*8 + ktl)*2 + kk)*64 + lane)*8 + j ]
// -> a wave's b-frag load (fixed e,n16,ktl,kk) is 64 lanes x 16B CONTIGUOUS (1KB).
__global__ void pack_xw_k(const f32x4* __restrict__ x, u16x4* __restrict__ xb,
                          const float* __restrict__ w, unsigned short* __restrict__ WtF) {
  __shared__ float tile[64][65];
  const int tid = threadIdx.x;
  if (blockIdx.x < 4096) {                      // pack x: 4096 blocks
    int gid = blockIdx.x * 256 + tid;
    f32x4 v = x[gid];
    u16x4 o;
    o[0] = f2bf(v[0]); o[1] = f2bf(v[1]); o[2] = f2bf(v[2]); o[3] = f2bf(v[3]);
    xb[gid] = o;
    return;
  }
  const int idx = blockIdx.x - 4096;            // pack w: 512 blocks
  const int kb = idx & 63, nb = idx >> 6;       // kb: 64 k-tiles over NCD; nb: 8 col-tiles
  const int e = kb >> 3, ktl = kb & 7;
#pragma unroll
  for (int it = 0; it < 16; ++it) {
    int u = it * 256 + tid;
    int r = u >> 6, cc = u & 63;                // k-in-tile, col-in-tile
    tile[r][cc] = w[(size_t)(e * 512 + ktl * 64 + r) * DOUT + nb * 64 + cc];
  }
  __syncthreads();
#pragma unroll
  for (int it = 0; it < 2; ++it) {
    int c = it * 256 + tid;                     // 512 chunks of 8 elems
    int n16l = c >> 7, kk = (c >> 6) & 1, l = c & 63;
    int l15 = l & 15, lhi = l >> 4;
    int col_in = n16l * 16 + l15;
    int k_in   = kk * 32 + lhi * 8;
    int n16    = nb * 4 + n16l;
    u16x4 o0, o1;
    o0[0] = f2bf(tile[k_in + 0][col_in]); o0[1] = f2bf(tile[k_in + 1][col_in]);
    o0[2] = f2bf(tile[k_in + 2][col_in]); o0[3] = f2bf(tile[k_in + 3][col_in]);
    o1[0] = f2bf(tile[k_in + 4][col_in]); o1[1] = f2bf(tile[k_in + 5][col_in]);
    o1[2] = f2bf(tile[k_in + 6][col_in]); o1[3] = f2bf(tile[k_in + 7][col_in]);
    size_t base = ((((size_t)e * 32 + n16) * 8 + ktl) * 2 + kk) * 512 + l * 8;
    *(u16x4*)(WtF + base)     = o0;
    *(u16x4*)(WtF + base + 4) = o1;
  }
}

// ---- fused GEMM: part_s = (wt .* x) @ W', 256x256 tile, K=1024 (split-K 4) ----
// r10: B NEVER touches LDS — b-frags are coalesced 1KB register loads from the
// frag-ordered WtF (L1/L2-resident; unique 32KB/tile/block, wm-pairs share).
// LDS carries only A (2 slots x 32KB, r7's measured-0-conflict swizzle:
// phys chunk = logical ^ (row&7), both on ds_write and frag read).
// Per tile (ONE raw barrier):
//   RD_A kk0 (8 ds) | issue b1q | lgkm+schedbar | 32 MFMA kk0
//   RD_A kk1 (8 ds) | SCALE A(t+1)->other slot (compiler waits A regs) |
//   AREGS(t+2) | lgkm+schedbar | 32 MFMA kk1 (compiler waits b1q)
//   issue b0q(t+1) [register loads legally cross raw s_barrier] | s_barrier
// NO manual vmcnt anywhere — compiler scoreboard manages all VMEM waits.
__global__ __launch_bounds__(512, 2) void gemm_k(
    const unsigned short* __restrict__ xb,   // [B_][DIN] bf16
    const unsigned short* __restrict__ WtF,  // frag-ordered weights
    const float* __restrict__ wt,            // [B_][NC] f32
    unsigned short* __restrict__ part) {     // [KSPL][B_][DOUT] bf16
  extern __shared__ char smem[];
  const int tid  = threadIdx.x;
  const int lane = tid & 63, wid = tid >> 6;
  const int wm = wid >> 2, wn = wid & 3;       // 2 x 4 wave grid
  const int l15 = lane & 15, lhi = lane >> 4;

  const int n0   = blockIdx.x;                 // 256 blocks
  const int by   = n0 >> 3;                    // 0..31
  const int bx   = (n0 >> 2) & 1;              // 0..1
  const int ks   = n0 & 3;                     // K-chunk: experts 2ks, 2ks+1
  const int brow = by * 256, bcol = bx * 256;

  // ---- A staging (reg->scale->swizzled ds_write), r7 layout verbatim ----
  const int srow = tid >> 3, schunk = tid & 7;
  const int swz  = schunk ^ (srow & 7);
  const unsigned short* gA = xb + (size_t)(brow + srow) * DIN + schunk * 8;
  const int adst_off = srow * 128 + swz * 16;  // + slot + P*8192

  // ---- B frag-load bases (per wave n16 = bx*16 + wn*4 + n) ----
  const unsigned short* bn0 = WtF + (size_t)(ks * 2) * 262144
                                  + (size_t)(bx * 16 + wn * 4 + 0) * 8192 + lane * 8;
  const unsigned short* bn1 = bn0 + 8192;
  const unsigned short* bn2 = bn0 + 16384;
  const unsigned short* bn3 = bn0 + 24576;

  // routing weights for this block's rows x 2 experts (held in VGPRs)
  const float* wtp = wt + (size_t)(brow + srow) * NC + ks * 2;
  const float wtv0_0 = wtp[0],            wtv1_0 = wtp[1];
  const float wtv0_1 = wtp[64 * NC],      wtv1_1 = wtp[64 * NC + 1];
  const float wtv0_2 = wtp[128 * NC],     wtv1_2 = wtp[128 * NC + 1];
  const float wtv0_3 = wtp[192 * NC],     wtv1_3 = wtp[192 * NC + 1];

  f32x4 acc[8][4] = {};
  s16x8 areg0, areg1, areg2, areg3;
  s16x8 a[8], b0q[4], b1q[4];
  const int x7    = l15 & 7;
  const int pc0   = (lhi ^ x7) * 16;           // phys chunk byte-offset, kk=0
  const int pc1   = ((4 + lhi) ^ x7) * 16;     // kk=1
  const int abase = (wm * 128 + l15) * 128;    // row stride 128B, a[m] +m*2048

#define LOAD_B(BQ, et, ktl, kk) {                                            \
    const size_t o_ = (size_t)(et) * 262144 + ((ktl) * 2 + (kk)) * 512;      \
    BQ[0] = *(const s16x8*)(bn0 + o_);                                       \
    BQ[1] = *(const s16x8*)(bn1 + o_);                                       \
    BQ[2] = *(const s16x8*)(bn2 + o_);                                       \
    BQ[3] = *(const s16x8*)(bn3 + o_); }
#define LOAD_AREGS(kt) {                                                     \
    const unsigned short* s_ = gA + ((kt) & 7) * 64;                         \
    areg0 = *(const s16x8*)(s_);                                             \
    areg1 = *(const s16x8*)(s_ + (size_t) 64 * DIN);                         \
    areg2 = *(const s16x8*)(s_ + (size_t)128 * DIN);                         \
    areg3 = *(const s16x8*)(s_ + (size_t)192 * DIN); }
#define SCALE_STORE(AR, S, P, slotb) {                                       \
    u32x4 v_;                                                                \
    v_[0] = cvtpk(bf2f((unsigned short)AR[0]) * (S),                         \
                  bf2f((unsigned short)AR[1]) * (S));                        \
    v_[1] = cvtpk(bf2f((unsigned short)AR[2]) * (S),                         \
                  bf2f((unsigned short)AR[3]) * (S));                        \
    v_[2] = cvtpk(bf2f((unsigned short)AR[4]) * (S),                         \
                  bf2f((unsigned short)AR[5]) * (S));                        \
    v_[3] = cvtpk(bf2f((unsigned short)AR[6]) * (S),                         \
                  bf2f((unsigned short)AR[7]) * (S));                        \
    *(u32x4*)(smem + (slotb) + adst_off + (P) * 8192) = v_; }
#define SCALE_WRITE_ALL(e_, slotb) {                                         \
    SCALE_STORE(areg0, (e_) ? wtv1_0 : wtv0_0, 0, slotb);                    \
    SCALE_STORE(areg1, (e_) ? wtv1_1 : wtv0_1, 1, slotb);                    \
    SCALE_STORE(areg2, (e_) ? wtv1_2 : wtv0_2, 2, slotb);                    \
    SCALE_STORE(areg3, (e_) ? wtv1_3 : wtv0_3, 3, slotb); }
#define RD_A8(slotb, PC) {                                                   \
    const char* pa_ = smem + (slotb) + abase + (PC);                         \
    _Pragma("unroll") for (int m = 0; m < 8; ++m)                            \
      a[m] = *(const s16x8*)(pa_ + m * 2048); }
#define MFMA_HALF(BQ)                                                        \
    _Pragma("unroll") for (int m = 0; m < 8; ++m)                            \
      _Pragma("unroll") for (int n = 0; n < 4; ++n)                          \
        acc[m][n] = __builtin_amdgcn_mfma_f32_16x16x32_bf16(                 \
            a[m], BQ[n], acc[m][n], 0, 0, 0);
#define BAR()   __builtin_amdgcn_s_barrier()
#define PRIO1() __builtin_amdgcn_s_setprio(1)
#define PRIO0() __builtin_amdgcn_s_setprio(0)
#define SBAR0() __builtin_amdgcn_sched_barrier(0)
#define WAITL() asm volatile("s_waitcnt lgkmcnt(0)" ::: "memory")

  // ---- prologue: A(0) scale->slot0, A(1) in flight, b0q(0) in flight ----
  LOAD_AREGS(0);
  SCALE_WRITE_ALL(0, 0);          // compiler waits A(0) regs
  LOAD_AREGS(1);
  LOAD_B(b0q, 0, 0, 0);
  WAITL();                        // ds_writes drained
  BAR();                          // raw: AREGS(1)+b0q legally in flight

  for (int t = 0; t < 16; ++t) {
    const int ct = (t & 1) * 32768, ot = 32768 - ct;
    const int ktl = t & 7, et = t >> 3;
    // ---- kk0 ----
    RD_A8(ct, pc0);
    LOAD_B(b1q, et, ktl, 1);
    WAITL(); SBAR0();
    PRIO1(); MFMA_HALF(b0q); PRIO0();
    // ---- kk1 ----
    RD_A8(ct, pc1);
    if (t < 15) {
      SCALE_WRITE_ALL(((t + 1) >> 3), ot);   // compiler waits A(t+1) regs
      if (t < 14) LOAD_AREGS(t + 2);
    }
    WAITL(); SBAR0();
    PRIO1(); MFMA_HALF(b1q); PRIO0();
    if (t < 15) LOAD_B(b0q, ((t + 1) >> 3), ((t + 1) & 7), 0);
    BAR();                        // writes to ot drained by WAITL above
  }

  // ---- epilogue: repack via LDS, then full-line dwordx4 stores ----
  __syncthreads();
  unsigned short* Cs = (unsigned short*)smem;   // [256][264] bf16
#pragma unroll
  for (int m = 0; m < 8; ++m)
#pragma unroll
    for (int n = 0; n < 4; ++n) {
      const int row = wm * 128 + m * 16 + lhi * 4;
      const int col = wn * 64 + n * 16 + l15;
      f32x4 v = acc[m][n];
#pragma unroll
      for (int j = 0; j < 4; ++j)
        Cs[(row + j) * 264 + col] = f2bf(v[j]);
    }
  __syncthreads();
  unsigned short* pc = part + (size_t)ks * (B_ * DOUT) + (size_t)brow * DOUT + bcol;
#pragma unroll
  for (int it = 0; it < 16; ++it) {
    const int u = it * 512 + tid;
    const int row = u >> 5, cu = (u & 31) * 8;
    f32x4 v = *(const f32x4*)(Cs + row * 264 + cu);
    *(f32x4*)(pc + (size_t)row * DOUT + cu) = v;
  }
#undef LOAD_B
#undef LOAD_AREGS
#undef SCALE_STORE
#undef SCALE_WRITE_ALL
#undef RD_A8
#undef MFMA_HALF
#undef BAR
#undef PRIO1
#undef PRIO0
#undef SBAR0
#undef WAITL
}

// -------- reduce: out = sum_s part_s + sum_c wt[b][c]*bias[c] --------
__global__ void reduce_k(const unsigned short* __restrict__ part,
                         const float* __restrict__ wt,
                         const float* __restrict__ bias,
                         float* __restrict__ out) {
  int gid = blockIdx.x * 256 + threadIdx.x;
  int b = gid >> 7;
  int o4 = (gid & 127) << 2;
  float w8[8];
  *(f32x4*)w8       = *(const f32x4*)(wt + (size_t)b * NC);
  *(f32x4*)(w8 + 4) = *(const f32x4*)(wt + (size_t)b * NC + 4);
  f32x4 acc = {0.f, 0.f, 0.f, 0.f};
  const size_t off = (size_t)b * DOUT + o4;
#pragma unroll
  for (int s = 0; s < KSPL; ++s) {
    u16x4 p = *(const u16x4*)(part + (size_t)s * (B_ * DOUT) + off);
#pragma unroll
    for (int i = 0; i < 4; ++i) acc[i] += bf2f(p[i]);
  }
#pragma unroll
  for (int cc = 0; cc < NC; ++cc) {
    f32x4 bi = *(const f32x4*)(bias + cc * DOUT + o4);
#pragma unroll
    for (int i = 0; i < 4; ++i) acc[i] += w8[cc] * bi[i];
  }
  *(f32x4*)(out + off) = acc;
}

// ---------------- fallback if ws too small ----------------
__global__ void bias_only_k(const float* __restrict__ wt,
                            const float* __restrict__ bias,
                            float* __restrict__ out) {
  int gid = blockIdx.x * 256 + threadIdx.x;
  int b = gid >> 7;
  int o4 = (gid & 127) << 2;
  float w8[8];
  *(f32x4*)w8       = *(const f32x4*)(wt + (size_t)b * NC);
  *(f32x4*)(w8 + 4) = *(const f32x4*)(wt + (size_t)b * NC + 4);
  f32x4 acc = {0.f, 0.f, 0.f, 0.f};
#pragma unroll
  for (int cc = 0; cc < NC; ++cc) {
    f32x4 bi = *(const f32x4*)(bias + cc * DOUT + o4);
#pragma unroll
    for (int i = 0; i < 4; ++i) acc[i] += w8[cc] * bi[i];
  }
  *(f32x4*)(out + (size_t)b * DOUT + o4) = acc;
}

extern "C" void kernel_launch(void* const* d_in, const int* in_sizes, int n_in,
                              void* d_out, int out_size, void* d_ws, size_t ws_size,
                              hipStream_t stream) {
  const float *x = nullptr, *wtc = nullptr, *w = nullptr, *bias = nullptr;
  for (int i = 0; i < n_in; ++i) {
    switch (in_sizes[i]) {
      case B_ * DIN:        x    = (const float*)d_in[i]; break;
      case B_ * NC:         wtc  = (const float*)d_in[i]; break;
      case NC * DIN * DOUT: w    = (const float*)d_in[i]; break;
      case NC * DOUT:       bias = (const float*)d_in[i]; break;
    }
  }
  float* out = (float*)d_out;

  const size_t XB_ELEMS   = (size_t)B_ * DIN;
  const size_t WT_ELEMS   = (size_t)NC * DIN * DOUT;
  const size_t PART_ELEMS = (size_t)KSPL * B_ * DOUT;
  const size_t need = (XB_ELEMS + WT_ELEMS + PART_ELEMS) * sizeof(unsigned short);

  if (ws_size < need) {
    bias_only_k<<<(B_ * DOUT / 4) / 256, 256, 0, stream>>>(wtc, bias, out);
    return;
  }

  unsigned short* xb   = (unsigned short*)d_ws;
  unsigned short* WtF  = xb + XB_ELEMS;
  unsigned short* part = WtF + WT_ELEMS;

  const int GEMM_LDS = 256 * 264 * 2;   // 135168 B (K-loop uses first 65536)
  (void)hipFuncSetAttribute((const void*)gemm_k,
                            hipFuncAttributeMaxDynamicSharedMemorySize, GEMM_LDS);

  pack_xw_k<<<4096 + 512, 256, 0, stream>>>((const f32x4*)x, (u16x4*)xb, w, WtF);
  gemm_k<<<256, 512, GEMM_LDS, stream>>>(xb, WtF, wtc, part);
  reduce_k<<<(B_ * DOUT / 4) / 256, 256, 0, stream>>>(part, wtc, bias, out);
}